// Round 1
// baseline (110.065 us; speedup 1.0000x reference)
//
#include <hip/hip_runtime.h>

#define NGRAPHS 1024
#define DP 1024  // D*P floats per node row (4 KiB)

// Exclusive prefix sum of counts -> per-graph start offsets.
__global__ __launch_bounds__(1024) void scan_kernel(const int* __restrict__ counts,
                                                    int* __restrict__ offs) {
    __shared__ int s[NGRAPHS];
    const int t = threadIdx.x;
    const int v = counts[t];
    s[t] = v;
    __syncthreads();
    for (int d = 1; d < NGRAPHS; d <<= 1) {
        int x = 0;
        if (t >= d) x = s[t - d];
        __syncthreads();
        if (t >= d) s[t] += x;
        __syncthreads();
    }
    offs[t] = s[t] - v;  // exclusive start
}

// One block per graph. Thread t streams float4 at flat index 4t of each node
// row (coalesced), accumulates, then a one-shot LDS transpose maps
// input-flat i = p*256+d  ->  output o = d*4+p, stored as one float4/thread.
__global__ __launch_bounds__(256) void pool_kernel(const float4* __restrict__ f4,
                                                   const int* __restrict__ counts,
                                                   const int* __restrict__ offs,
                                                   float4* __restrict__ out4) {
    const int g = blockIdx.x;
    const int t = threadIdx.x;
    const int start = offs[g];
    const int cnt = counts[g];

    const float4* p = f4 + (size_t)start * 256 + t;
    float ax0 = 0.f, ay0 = 0.f, az0 = 0.f, aw0 = 0.f;
    float ax1 = 0.f, ay1 = 0.f, az1 = 0.f, aw1 = 0.f;

    int n = 0;
    for (; n + 2 <= cnt; n += 2) {
        float4 v0 = p[0];
        float4 v1 = p[256];
        p += 512;
        ax0 += v0.x; ay0 += v0.y; az0 += v0.z; aw0 += v0.w;
        ax1 += v1.x; ay1 += v1.y; az1 += v1.z; aw1 += v1.w;
    }
    if (n < cnt) {
        float4 v0 = p[0];
        ax0 += v0.x; ay0 += v0.y; az0 += v0.z; aw0 += v0.w;
    }

    const float inv = 1.0f / (float)cnt;
    float4 a;
    a.x = (ax0 + ax1) * inv;
    a.y = (ay0 + ay1) * inv;
    a.z = (az0 + az1) * inv;
    a.w = (aw0 + aw1) * inv;

    __shared__ float lds[DP];
    reinterpret_cast<float4*>(lds)[t] = a;   // lds[i] = mean at input-flat i
    __syncthreads();

    // out element o = 4t+k  ->  d = t, p = k  ->  value = lds[k*256 + t]
    float4 o;
    o.x = lds[t];
    o.y = lds[256 + t];
    o.z = lds[512 + t];
    o.w = lds[768 + t];
    out4[(size_t)g * 256 + t] = o;
}

extern "C" void kernel_launch(void* const* d_in, const int* in_sizes, int n_in,
                              void* d_out, int out_size, void* d_ws, size_t ws_size,
                              hipStream_t stream) {
    const float* features = (const float*)d_in[0];
    const int* counts = (const int*)d_in[1];
    int* offs = (int*)d_ws;  // 1024 ints of scratch

    scan_kernel<<<1, 1024, 0, stream>>>(counts, offs);
    pool_kernel<<<NGRAPHS, 256, 0, stream>>>((const float4*)features, counts, offs,
                                             (float4*)d_out);
}